// Round 7
// baseline (147.382 us; speedup 1.0000x reference)
//
#include <hip/hip_runtime.h>

// Problem constants (fixed by setup_inputs in the reference)
#define B_  8
#define N_  3072
#define C_  256
#define H_  128
#define W_  96
#define HW_ (H_ * W_)
#define NC_ (B_ * HW_)          // 98304 cells (~78% are EMPTY: 0.25 tokens/cell)
#define NT_ (B_ * N_)           // 24576 tokens
#define EPSF 1e-6f

// Gaussian 3x3, sigma=2 (normalized): center, edge, corner
#define KW0 0.13080118f
#define KW1 0.11543166f
#define KW2 0.10186807f

// ws layout (u32 units) — total 221,956 u32 = 887,824 B, under the 900,104 B
// bound proven safe by round 4. desc overlays Acur (dead after fill_bins).
#define OFF_ASTART 0
#define OFF_WORK   98308                  // 16B-aligned
#define OFF_ACUR   OFF_WORK               // NC_ u32, dead after fill_bins
#define OFF_DESC   OFF_WORK               // NC_ u32 overlay (desc_k runs after fill_bins)
#define OFF_BSUM   (OFF_WORK + NC_)       // 384, dead after scanB
#define OFF_BOFF   (OFF_WORK + NC_ + 384) // 384, dead after scanC
#define OFF_TOKS   (OFF_WORK + NC_ + 768) // = 197380, NT_ u32

__device__ __forceinline__ void token_cell(const float* __restrict__ loc, int token,
                                           int& b, int& ix, int& iy) {
    b = token / N_;
    const float lx = fminf(fmaxf(loc[2 * token + 0], -1.0f), 1.0f);
    const float ly = fminf(fmaxf(loc[2 * token + 1], -1.0f), 1.0f);
    const float px = 0.5f * (lx + 1.0f) * (float)W_ - 0.5f;
    const float py = 0.5f * (ly + 1.0f) * (float)H_ - 0.5f;
    ix = (int)rintf(px); ix = min(max(ix, 0), W_ - 1);   // rintf = round-half-even = jnp.round
    iy = (int)rintf(py); iy = min(max(iy, 0), H_ - 1);
}

// Pass 1: histogram tokens into cells
__global__ void count_k(const float* __restrict__ loc, unsigned* __restrict__ cnts) {
    const int token = blockIdx.x * 256 + threadIdx.x;   // NT_ threads
    int b, ix, iy;
    token_cell(loc, token, b, ix, iy);
    atomicAdd(&cnts[b * HW_ + iy * W_ + ix], 1u);
}

// Pass 2a: per-block (256-cell) sums
__global__ void scanA(const unsigned* __restrict__ cnts, unsigned* __restrict__ Bsum) {
    const int i = blockIdx.x * 256 + threadIdx.x;
    int c = (int)cnts[i];
    #pragma unroll
    for (int off = 32; off > 0; off >>= 1) c += __shfl_down(c, off, 64);
    __shared__ int s[4];
    if ((threadIdx.x & 63) == 0) s[threadIdx.x >> 6] = c;
    __syncthreads();
    if (threadIdx.x == 0) Bsum[blockIdx.x] = (unsigned)(s[0] + s[1] + s[2] + s[3]);
}

// Pass 2b: exclusive scan of the 384 block sums (single block)
__global__ void scanB(const unsigned* __restrict__ Bsum, unsigned* __restrict__ Boff) {
    __shared__ unsigned s[512];
    const int t = threadIdx.x;
    const unsigned v = (t < 384) ? Bsum[t] : 0u;
    s[t] = v;
    __syncthreads();
    #pragma unroll
    for (int off = 1; off < 512; off <<= 1) {
        const unsigned a = (t >= off) ? s[t - off] : 0u;
        __syncthreads();
        s[t] += a;
        __syncthreads();
    }
    if (t < 384) Boff[t] = s[t] - v;   // exclusive
}

// Pass 2c: per-block exclusive scan + block offset -> Astart (and cursor copy)
__global__ void scanC(const unsigned* __restrict__ Boff,
                      unsigned* __restrict__ Astart, unsigned* __restrict__ Acur) {
    __shared__ unsigned s[256];
    const int t = threadIdx.x;
    const int i = blockIdx.x * 256 + t;
    const unsigned v = Acur[i];        // counts currently live in Acur
    s[t] = v;
    __syncthreads();
    #pragma unroll
    for (int off = 1; off < 256; off <<= 1) {
        const unsigned a = (t >= off) ? s[t - off] : 0u;
        __syncthreads();
        s[t] += a;
        __syncthreads();
    }
    const unsigned excl = s[t] - v + Boff[blockIdx.x];
    Astart[i] = excl;
    Acur[i]   = excl;                  // cursor starts at bin start
    if (i == 0) Astart[NC_] = NT_;     // total
}

// Pass 3: scatter token ids (packed with x) into bins
__global__ void fill_bins(const float* __restrict__ loc,
                          unsigned* __restrict__ Acur, unsigned* __restrict__ toks) {
    const int token = blockIdx.x * 256 + threadIdx.x;
    int b, ix, iy;
    token_cell(loc, token, b, ix, iy);
    const unsigned pos = atomicAdd(&Acur[b * HW_ + iy * W_ + ix], 1u);
    toks[pos] = ((unsigned)ix << 20) | (unsigned)token;
}

// Pass 3b: per-cell descriptor (NOT compacted — worst case is all cells).
// desc = 0 for nonempty; for empty: (neighbor-nonempty mask << 1) | 1.
// Overlays the dead Acur region — must launch after fill_bins.
__global__ void desc_k(const unsigned* __restrict__ Astart, unsigned* __restrict__ desc) {
    const int i = blockIdx.x * 256 + threadIdx.x;   // NC_ threads
    if (Astart[i + 1] > Astart[i]) { desc[i] = 0u; return; }
    const int b = i / HW_;
    const int r = i - b * HW_;                      // y*W + x
    const int y = r / W_, x = r - y * W_;

    const int DY[8] = {-1, -1, -1, 0, 0, 1, 1, 1};
    const int DX[8] = {-1, 0, 1, -1, 1, -1, 0, 1};
    unsigned m = 0;
    #pragma unroll
    for (int j = 0; j < 8; ++j) {
        const int yy = y + DY[j], xn = x + DX[j];
        if (yy < 0 || yy >= H_ || xn < 0 || xn >= W_) continue;
        const int nc = i + DY[j] * W_ + DX[j];
        if (Astart[nc + 1] > Astart[nc]) m |= 1u << j;
    }
    desc[i] = (m << 1) | 1u;
}

// Pass 4: per-(b,y) row gather + normalize + transposed coalesced NCHW write.
__global__ __launch_bounds__(256) void gather_norm(const float* __restrict__ xf,
        const unsigned* __restrict__ Astart, const unsigned* __restrict__ toks,
        float* __restrict__ out) {
    const int blk = blockIdx.x;          // 0..1023 = (b,y)
    const int b = blk >> 7;
    const int y = blk & 127;
    const int tid = threadIdx.x;         // channel
    const int rowbase = b * HW_ + y * W_;
    __shared__ float tile[32][257];
    __shared__ unsigned rs[33];

    for (int xt = 0; xt < 3; ++xt) {     // 3 tiles of 32 x-positions
        const int xbase = xt * 32;
        if (tid < 33) rs[tid] = Astart[rowbase + xbase + tid];
        #pragma unroll
        for (int xi = 0; xi < 32; ++xi) tile[xi][tid] = 0.0f;
        __syncthreads();

        const unsigned r0 = rs[0], r1 = rs[32];
        int cur_x = -1;
        float acc = 0.0f;
        for (unsigned p = r0; p < r1; p += 4) {
            unsigned vv[4]; float ff[4];
            #pragma unroll
            for (int j = 0; j < 4; ++j)
                if (p + j < r1) vv[j] = toks[p + j];
            #pragma unroll
            for (int j = 0; j < 4; ++j)
                if (p + j < r1) ff[j] = xf[(size_t)(vv[j] & 0xFFFFFu) * C_ + tid];
            #pragma unroll
            for (int j = 0; j < 4; ++j) {
                if (p + j >= r1) break;
                const int x = (int)(vv[j] >> 20);
                if (x != cur_x) {
                    if (cur_x >= 0) tile[cur_x & 31][tid] = acc;
                    acc = 0.0f;
                    cur_x = x;
                }
                acc += ff[j];
            }
        }
        if (cur_x >= 0) tile[cur_x & 31][tid] = acc;
        __syncthreads();

        const int x_off = tid & 31, cg = tid >> 5;
        const unsigned k = rs[x_off + 1] - rs[x_off];
        const float rcp = 1.0f / ((float)k + EPSF);
        const size_t obase = ((size_t)(b * C_)) * HW_ + y * W_ + xbase + x_off;
        #pragma unroll
        for (int cp = 0; cp < 32; ++cp) {
            const int c = cp * 8 + cg;
            out[obase + (size_t)c * HW_] = tile[x_off][c] * rcp;
        }
        __syncthreads();
    }
}

// Pass 5: fill empty cells. Block = 64 consecutive cells x 256 channels
// (wave wv handles channels [wv*64, wv*64+64), lanes = cells -> neighbor loads
// coalesce per direction). Nonempty lanes exec-mask off immediately.
// Race-free: nonzero-weight reads touch only nonempty cells (never written
// here); zero-weight reads are clamped in-bounds and multiply to 0 (4B loads
// are atomic, all values finite after gather_norm wrote the full surface).
__global__ __launch_bounds__(256) void fill_desc(float* __restrict__ out,
        const unsigned* __restrict__ desc) {
    const int lane = threadIdx.x & 63;
    const int wv = threadIdx.x >> 6;      // wave 0..3 -> channel quarter
    const int cell = (blockIdx.x << 6) + lane;    // 1536 blocks x 64 cells
    const unsigned d = desc[cell];
    if (!(d & 1u)) return;                // nonempty cell: keep normalized mean
    const unsigned m = d >> 1;

    const int b = cell / HW_;
    const int r = cell - b * HW_;
    const int y = r / W_, x = r - y * W_;

    // recompute normalization from mask (amortized over 64 channels)
    const float msum = KW1 * (float)__popc(m & 0x5Au)    // edges: bits 1,3,4,6
                     + KW2 * (float)__popc(m & 0xA5u);   // corners: bits 0,2,5,7
    const float inv = 1.0f / (msum + EPSF);              // m==0 -> weights all 0
    const float w1r = KW1 * inv, w2r = KW2 * inv;

    const int oyu = (y > 0)      ? -W_ : 0;
    const int oyd = (y < H_ - 1) ?  W_ : 0;
    const int oxl = (x > 0)      ?  -1 : 0;
    const int oxr = (x < W_ - 1) ?   1 : 0;
    int jo[8];
    jo[0] = oyu + oxl; jo[1] = oyu; jo[2] = oyu + oxr;
    jo[3] = oxl;                    jo[4] = oxr;
    jo[5] = oyd + oxl; jo[6] = oyd; jo[7] = oyd + oxr;
    float w[8];
    w[0] = (m & 1u)   ? w2r : 0.0f;  w[1] = (m & 2u)   ? w1r : 0.0f;
    w[2] = (m & 4u)   ? w2r : 0.0f;  w[3] = (m & 8u)   ? w1r : 0.0f;
    w[4] = (m & 16u)  ? w1r : 0.0f;  w[5] = (m & 32u)  ? w2r : 0.0f;
    w[6] = (m & 64u)  ? w1r : 0.0f;  w[7] = (m & 128u) ? w2r : 0.0f;

    unsigned idx = (unsigned)(b * C_ * HW_ + r) + (unsigned)(wv * 64) * HW_;
    #pragma unroll 4
    for (int it = 0; it < 64; ++it, idx += HW_) {
        float fs = 0.0f;
        #pragma unroll
        for (int j = 0; j < 8; ++j) fs += w[j] * out[idx + (unsigned)jo[j]];
        out[idx] = fs;
    }
}

extern "C" void kernel_launch(void* const* d_in, const int* in_sizes, int n_in,
                              void* d_out, int out_size, void* d_ws, size_t ws_size,
                              hipStream_t stream) {
    const float* x   = (const float*)d_in[0];   // (B, N, C) f32
    const float* loc = (const float*)d_in[1];   // (B, N, 2) f32
    float* out = (float*)d_out;                 // (B, C, H, W) f32

    unsigned* W32 = (unsigned*)d_ws;
    unsigned* Astart = W32 + OFF_ASTART;
    unsigned* Acur   = W32 + OFF_ACUR;
    unsigned* Bsum   = W32 + OFF_BSUM;
    unsigned* Boff   = W32 + OFF_BOFF;
    unsigned* toks   = W32 + OFF_TOKS;
    unsigned* desc   = W32 + OFF_DESC;

    hipMemsetAsync(Acur, 0, (size_t)NC_ * sizeof(unsigned), stream);

    count_k  <<<NT_ / 256, 256, 0, stream>>>(loc, Acur);
    scanA    <<<NC_ / 256, 256, 0, stream>>>(Acur, Bsum);
    scanB    <<<1, 512, 0, stream>>>(Bsum, Boff);
    scanC    <<<NC_ / 256, 256, 0, stream>>>(Boff, Astart, Acur);
    fill_bins<<<NT_ / 256, 256, 0, stream>>>(loc, Acur, toks);
    // Acur is dead from here; desc_k overwrites its region.
    desc_k   <<<NC_ / 256, 256, 0, stream>>>(Astart, desc);

    gather_norm<<<B_ * H_, 256, 0, stream>>>(x, Astart, toks, out);

    fill_desc<<<NC_ / 64, 256, 0, stream>>>(out, desc);
}